// Round 2
// baseline (94.505 us; speedup 1.0000x reference)
//
#include <hip/hip_runtime.h>
#include <math.h>

#define LOG2PI_F 1.8378770664093453f
#define LOG2E_F  1.4426950408889634f
#define LN2_F    0.6931471805599453f
#define EXP_NEG1 0.36787944117144233f

#define TI   32      // i-rows per block (2 per thread: il and il+16)
#define JSP  16      // j-splits (grid.y)
#define JCH  128     // j-rows per block = B/JSP (B=2048)
#define ROWF 52      // floats per AC row: a[16] b[16] c[16] prod [pad 3]

__device__ __forceinline__ float exp2_(float x) { return __builtin_amdgcn_exp2f(x); }
__device__ __forceinline__ float log2_(float x) { return __builtin_amdgcn_logf(x); }

// ws layout (floats), nothing pre-zeroed:
//   Rs  [JSP][17][B]   per-jsplit partial sums, [c][i] transposed for coalescing
//   PPa [JSP] PPb [JSP]  per-(bx==0)-block lqzx / lprior partials
//   RP  [(B/TI)*JSP]     per-block recon partials
//   LPa [B/256] LPb [B/256]  per-block lqz / lqzp partials
//   cnt [1]              ticket counter (zeroed by k_main each launch)

#define DIM2(AQ, BQ, CQ, comp, dd, SA, SB) \
    e = fmaf(AQ.comp, va2[dd], BQ.comp * va[dd]); SA += e; sda[dd] = fmaf(CQ.comp, exp2_(e), sda[dd]); \
    e = fmaf(AQ.comp, vb2[dd], BQ.comp * vb[dd]); SB += e; sdb[dd] = fmaf(CQ.comp, exp2_(e), sdb[dd]);

// ---------------------------------------------------------------- main
// grid (B/TI, JSP); block 256 = 16 il x 16 jg.
// Phase A: recompute this block's AC j-slice straight into LDS (no global AC,
// no staging loads, no prep kernel). bx==0 blocks also emit lqzx/lprior
// partials; every block takes one float4 recon chunk.
// Phase B: 2-i-rows-per-thread pairwise loop (unchanged from round 1).
__global__ __launch_bounds__(256) void k_main(
        const float* __restrict__ mu, const float* __restrict__ lv,
        const float* __restrict__ z, const int* __restrict__ nds,
        const float4* __restrict__ x, const float4* __restrict__ r,
        float* __restrict__ Rs, float* __restrict__ PPa, float* __restrict__ PPb,
        float* __restrict__ RP, unsigned* __restrict__ cnt,
        int B, int n4) {
    __shared__ float sbuf[JCH * ROWF];      // 26.6 KB
    __shared__ float red[4][TI][17];        // 8.7 KB
    __shared__ float pra[4], prb[4], prr[4];

    const int tid  = threadIdx.x;
    const int lane = tid & 63, wv = tid >> 6;
    const int jbase = blockIdx.y * JCH;

    if (blockIdx.x == 0 && blockIdx.y == 0 && tid == 0) *cnt = 0u;

    // ---- phase A: AC coefficients for j in [jbase, jbase+JCH) into LDS
    float Nf = (float)(*nds);
    float Mf = (float)(B - 1);
    float strat = (Nf - Mf) / (Nf * Mf);
    float ga = 0.0f, gb = 0.0f;
    #pragma unroll
    for (int it = 0; it < (JCH * 16) / 256; ++it) {
        int item = it * 256 + tid;
        int jl = item >> 4, d = item & 15;
        int gi = jbase * 16 + item;                  // coalesced
        float m = mu[gi], l = lv[gi], zz = z[gi];
        float is = __expf(-l);
        float a = -0.5f * LOG2E_F * is;              // log2-domain
        float b = -2.0f * a * m;
        float ec = fmaf(-0.5f * LOG2E_F, l + LOG2PI_F, a * m * m);
        int j = jbase + jl;
        float w = (j == 0) ? (1.0f / Nf) : ((j == 1) ? strat : (1.0f / Mf));
        float* row = sbuf + jl * ROWF;
        row[d] = a;
        row[16 + d] = b;
        row[32 + d] = w * exp2_(ec);
        float es = ec;                               // lanes d=0..15 share j
        es += __shfl_xor(es, 1); es += __shfl_xor(es, 2);
        es += __shfl_xor(es, 4); es += __shfl_xor(es, 8);
        if (d == 0) row[48] = w * exp2_(es);
        if (blockIdx.x == 0) {                       // lqzx / lprior once per j
            float t = zz - m;
            ga += -0.5f * (fmaf(t * t, is, l) + LOG2PI_F);
            gb += -0.5f * (fmaf(zz * zz, EXP_NEG1, 1.0f) + LOG2PI_F);
        }
    }

    // ---- recon chunk: grid is exactly n4/256 blocks at B=2048,F=512
    float sr = 0.0f;
    const int nblk = gridDim.x * gridDim.y;
    const int bid  = blockIdx.y * gridDim.x + blockIdx.x;
    for (int idx = bid * 256 + tid; idx < n4; idx += nblk * 256) {
        float4 a4 = x[idx], b4 = r[idx];
        sr += fabsf(a4.x - b4.x) + fabsf(a4.y - b4.y) +
              fabsf(a4.z - b4.z) + fabsf(a4.w - b4.w);
    }
    #pragma unroll
    for (int off = 32; off > 0; off >>= 1) {
        sr += __shfl_down(sr, off);
        ga += __shfl_down(ga, off);
        gb += __shfl_down(gb, off);
    }
    if (lane == 0) { prr[wv] = sr; pra[wv] = ga; prb[wv] = gb; }

    // ---- load z rows for this block's i-tile (2 rows per thread)
    const int il = tid & 15;
    const int jg = tid >> 4;
    const int i0 = blockIdx.x * TI + il;
    float va[16], va2[16], vb[16], vb2[16];
    {
        const float4* zp = (const float4*)(z + (size_t)i0 * 16);
        float4 z0 = zp[0], z1 = zp[1], z2 = zp[2], z3 = zp[3];
        va[0]=z0.x; va[1]=z0.y; va[2]=z0.z; va[3]=z0.w;
        va[4]=z1.x; va[5]=z1.y; va[6]=z1.z; va[7]=z1.w;
        va[8]=z2.x; va[9]=z2.y; va[10]=z2.z; va[11]=z2.w;
        va[12]=z3.x; va[13]=z3.y; va[14]=z3.z; va[15]=z3.w;
        const float4* zq = (const float4*)(z + (size_t)(i0 + 16) * 16);
        float4 y0 = zq[0], y1 = zq[1], y2 = zq[2], y3 = zq[3];
        vb[0]=y0.x; vb[1]=y0.y; vb[2]=y0.z; vb[3]=y0.w;
        vb[4]=y1.x; vb[5]=y1.y; vb[6]=y1.z; vb[7]=y1.w;
        vb[8]=y2.x; vb[9]=y2.y; vb[10]=y2.z; vb[11]=y2.w;
        vb[12]=y3.x; vb[13]=y3.y; vb[14]=y3.z; vb[15]=y3.w;
        #pragma unroll
        for (int d = 0; d < 16; d++) { va2[d] = va[d] * va[d]; vb2[d] = vb[d] * vb[d]; }
    }

    float sda[16], sdb[16];
    #pragma unroll
    for (int d = 0; d < 16; d++) { sda[d] = 0.0f; sdb[d] = 0.0f; }
    float stA = 0.0f, stB = 0.0f;

    __syncthreads();    // sbuf ready + pr* ready

    if (tid == 0) {
        RP[bid] = prr[0] + prr[1] + prr[2] + prr[3];
        if (blockIdx.x == 0) {
            PPa[blockIdx.y] = pra[0] + pra[1] + pra[2] + pra[3];
            PPb[blockIdx.y] = prb[0] + prb[1] + prb[2] + prb[3];
        }
    }

    // ---- phase B: pairwise loop
    const int nk = JCH >> 4;                // 8
    for (int k = 0; k < nk; ++k) {
        const float* rp = sbuf + (jg + 16 * k) * ROWF;
        const float4* r4 = (const float4*)rp;
        float sa0 = 0.0f, sa1 = 0.0f, sb0 = 0.0f, sb1 = 0.0f, e;
        {   // dims 0-7
            float4 A0 = r4[0], A1 = r4[1], Bq0 = r4[4], Bq1 = r4[5], C0 = r4[8], C1 = r4[9];
            DIM2(A0, Bq0, C0, x, 0, sa0, sb0)  DIM2(A0, Bq0, C0, y, 1, sa1, sb1)
            DIM2(A0, Bq0, C0, z, 2, sa0, sb0)  DIM2(A0, Bq0, C0, w, 3, sa1, sb1)
            DIM2(A1, Bq1, C1, x, 4, sa0, sb0)  DIM2(A1, Bq1, C1, y, 5, sa1, sb1)
            DIM2(A1, Bq1, C1, z, 6, sa0, sb0)  DIM2(A1, Bq1, C1, w, 7, sa1, sb1)
        }
        {   // dims 8-15
            float4 A2 = r4[2], A3 = r4[3], Bq2 = r4[6], Bq3 = r4[7], C2 = r4[10], C3 = r4[11];
            DIM2(A2, Bq2, C2, x, 8, sa0, sb0)  DIM2(A2, Bq2, C2, y, 9, sa1, sb1)
            DIM2(A2, Bq2, C2, z, 10, sa0, sb0) DIM2(A2, Bq2, C2, w, 11, sa1, sb1)
            DIM2(A3, Bq3, C3, x, 12, sa0, sb0) DIM2(A3, Bq3, C3, y, 13, sa1, sb1)
            DIM2(A3, Bq3, C3, z, 14, sa0, sb0) DIM2(A3, Bq3, C3, w, 15, sa1, sb1)
        }
        float P = rp[48];
        stA = fmaf(P, exp2_(sa0 + sa1), stA);
        stB = fmaf(P, exp2_(sb0 + sb1), stB);
    }

    // reduce over jg within wave (jg bits 0-1 = lane bits 4-5)
    #pragma unroll
    for (int msk = 16; msk <= 32; msk <<= 1) {
        stA += __shfl_xor(stA, msk);
        stB += __shfl_xor(stB, msk);
        #pragma unroll
        for (int d = 0; d < 16; d++) {
            sda[d] += __shfl_xor(sda[d], msk);
            sdb[d] += __shfl_xor(sdb[d], msk);
        }
    }
    if (lane < 16) {
        red[wv][lane][0] = stA;
        red[wv][lane + 16][0] = stB;
        #pragma unroll
        for (int d = 0; d < 16; d++) {
            red[wv][lane][1 + d] = sda[d];
            red[wv][lane + 16][1 + d] = sdb[d];
        }
    }
    __syncthreads();
    // plain stores to this j-split's slice (transposed [c][i] layout)
    for (int t = tid; t < TI * 17; t += 256) {
        int il2 = t & 31, c = t >> 5;
        float s = red[0][il2][c] + red[1][il2][c] + red[2][il2][c] + red[3][il2][c];
        Rs[((size_t)blockIdx.y * 17 + c) * B + blockIdx.x * TI + il2] = s;
    }
}

// ---------------------------------------------------------------- tail
// One thread per i: sum JSP slices (coalesced), logs + W[B-2,0] patch
// (patch row recomputed inline from mu/lv since AC never hits global).
// Last block (fence + atomic ticket) folds all partials and writes out.
__global__ __launch_bounds__(256) void k_tail(
        const float* __restrict__ Rs, const float* __restrict__ mu,
        const float* __restrict__ lv, const float* __restrict__ z,
        const int* __restrict__ nds,
        const float* __restrict__ RP, const float* __restrict__ PPa,
        const float* __restrict__ PPb, float* __restrict__ LPa,
        float* __restrict__ LPb, unsigned* __restrict__ cnt,
        float* __restrict__ out, int B, int nRP, float invBF, float invB) {
    const int tid = threadIdx.x;
    const int i = blockIdx.x * 256 + tid;
    float S = 0.0f, Sd[16];
    #pragma unroll
    for (int d = 0; d < 16; d++) Sd[d] = 0.0f;
    for (int sp = 0; sp < JSP; ++sp) {
        const float* base = Rs + (size_t)sp * 17 * B + i;
        S += base[0];
        #pragma unroll
        for (int d = 0; d < 16; d++) Sd[d] += base[(size_t)(1 + d) * B];
    }

    float Nf = (float)(*nds);
    float Mf = (float)(B - 1);
    float strat = (Nf - Mf) / (Nf * Mf);
    if (i == B - 2) {
        // main folded w0 = 1/N into j=0, but W[B-2,0] = strat: add delta.
        float dw = strat - 1.0f / Nf;
        const float* vv = z + (size_t)i * 16;
        float s2 = 0.0f;
        #pragma unroll
        for (int d = 0; d < 16; d++) {
            float m = mu[d], l = lv[d];
            float is = __expf(-l);
            float a = -0.5f * LOG2E_F * is;
            float b = -2.0f * a * m;
            float ec = fmaf(-0.5f * LOG2E_F, l + LOG2PI_F, a * m * m);
            float vd = vv[d];
            float ee = fmaf(a, vd * vd, b * vd) + ec;
            s2 += ee;
            Sd[d] += dw * exp2_(ee);
        }
        S += dw * exp2_(s2);
    }

    float lqz = log2_(S) * LN2_F;
    float lqzp = 0.0f;
    #pragma unroll
    for (int d = 0; d < 16; d++) lqzp += log2_(Sd[d]);
    lqzp *= LN2_F;

    #pragma unroll
    for (int off = 32; off > 0; off >>= 1) {
        lqz += __shfl_down(lqz, off);
        lqzp += __shfl_down(lqzp, off);
    }
    __shared__ float ra[4], rb[4];
    const int lane = tid & 63, wv = tid >> 6;
    if (lane == 0) { ra[wv] = lqz; rb[wv] = lqzp; }
    __syncthreads();
    if (tid == 0) {
        LPa[blockIdx.x] = ra[0] + ra[1] + ra[2] + ra[3];
        LPb[blockIdx.x] = rb[0] + rb[1] + rb[2] + rb[3];
    }

    // ---- ticket: last block performs the final reduction
    __threadfence();
    __shared__ unsigned lastf;
    if (tid == 0) lastf = (atomicAdd(cnt, 1u) == (unsigned)gridDim.x - 1u) ? 1u : 0u;
    __syncthreads();
    if (lastf) {
        __threadfence();
        float s0 = 0.0f, s1 = 0.0f, s2 = 0.0f, s3 = 0.0f, s4 = 0.0f;
        for (int t = tid; t < nRP; t += 256) s0 += RP[t];
        for (int t = tid; t < JSP; t += 256) { s1 += PPa[t]; s2 += PPb[t]; }
        for (int t = tid; t < (int)gridDim.x; t += 256) { s3 += LPa[t]; s4 += LPb[t]; }
        #pragma unroll
        for (int off = 32; off > 0; off >>= 1) {
            s0 += __shfl_down(s0, off); s1 += __shfl_down(s1, off);
            s2 += __shfl_down(s2, off); s3 += __shfl_down(s3, off);
            s4 += __shfl_down(s4, off);
        }
        __shared__ float fr[4][5];
        if (lane == 0) {
            fr[wv][0] = s0; fr[wv][1] = s1; fr[wv][2] = s2;
            fr[wv][3] = s3; fr[wv][4] = s4;
        }
        __syncthreads();
        if (tid == 0) {
            float R  = fr[0][0] + fr[1][0] + fr[2][0] + fr[3][0];
            float GA = fr[0][1] + fr[1][1] + fr[2][1] + fr[3][1];
            float GB = fr[0][2] + fr[1][2] + fr[2][2] + fr[3][2];
            float LZ = fr[0][3] + fr[1][3] + fr[2][3] + fr[3][3];
            float LQ = fr[0][4] + fr[1][4] + fr[2][4] + fr[3][4];
            out[0] = R * invBF + (GA + 3.0f * LZ - 3.0f * LQ - GB) * invB;
        }
    }
}

extern "C" void kernel_launch(void* const* d_in, const int* in_sizes, int n_in,
                              void* d_out, int out_size, void* d_ws, size_t ws_size,
                              hipStream_t stream) {
    const float* x   = (const float*)d_in[0];
    const float* rec = (const float*)d_in[1];
    const float* mu  = (const float*)d_in[2];
    const float* lv  = (const float*)d_in[3];
    const float* z   = (const float*)d_in[4];
    const int*   nds = (const int*)d_in[5];

    const int BD = in_sizes[2];        // B * 16
    const int B  = BD / 16;
    const int BF = in_sizes[0];        // B * F
    const int n4 = BF / 4;
    const int nRP = (B / TI) * JSP;    // 1024
    const int logBlks = B / 256;       // 8

    float* Rs  = (float*)d_ws;                         // JSP*17*B
    float* PPa = Rs + (size_t)JSP * 17 * B;            // JSP
    float* PPb = PPa + JSP;
    float* RP  = PPb + JSP;                            // nRP
    float* LPa = RP + nRP;
    float* LPb = LPa + logBlks;
    unsigned* cnt = (unsigned*)(LPb + logBlks);

    dim3 gm(B / TI, JSP);
    k_main<<<gm, 256, 0, stream>>>(mu, lv, z, nds,
        (const float4*)x, (const float4*)rec, Rs, PPa, PPb, RP, cnt, B, n4);
    k_tail<<<logBlks, 256, 0, stream>>>(Rs, mu, lv, z, nds, RP, PPa, PPb,
        LPa, LPb, cnt, (float*)d_out, B, nRP,
        1.0f / (float)BF, 1.0f / (float)B);
}